// Round 1
// 506.472 us; speedup vs baseline: 1.0081x; 1.0081x over previous
//
#include <hip/hip_runtime.h>
#include <cstddef>
#include <cstdint>

// ---------------------------------------------------------------------------
// GraphClassifier round 4.
// fc1 rebuilt: 1024-thread blocks (16 waves = kg4 x ng4 in-block split-K),
// BM=32, full K per block, LDS kg-reduction + fused bias/ReLU epilogue
// (fc1_reduce kernel + fp16 partial traffic eliminated). Inner loop uses
// counted s_waitcnt vmcnt(4) so the A-prefetch stays in flight across the
// MFMA phase (sched_barrier(0)-fenced to pin issue order).
// fc2/fc3/BN/attention/head unchanged from round 3.
// ---------------------------------------------------------------------------

#define NN 4096
#define HDIM 64
#define ENC_OUT (NN * HDIM)   // 262144 = 2^18

typedef _Float16 half8 __attribute__((ext_vector_type(8)));
typedef _Float16 half4 __attribute__((ext_vector_type(4)));
typedef float v4f __attribute__((ext_vector_type(4)));

__device__ __forceinline__ void gld_lds16(const void* g, void* l) {
    __builtin_amdgcn_global_load_lds(
        (const __attribute__((address_space(1))) void*)g,
        (__attribute__((address_space(3))) void*)l, 16, 0, 0);
}

struct GemmP {
    const void*     A[2];     // fp32 (fc1) or fp16, row-major [M,lda]
    const _Float16* B[2];     // weight fp16, row-major [N,lda]
    const float*    bias[2];
    void*           C[2];     // OUT=0: fp16 per-enc; OUT=1: fp32 per-enc
};

// ---------------------------------------------------------------------------
// fc1: C[m,n] = relu(bias[n] + sum_k A[m,k]*B[n,k]),  M=4096 N=256 K=4096.
// Block: 1024 thr = 16 waves, wave w -> (kg=w>>2, ng=w&3).
// Wave computes partial C[32, ng*64 .. +64) over k in [kg*1024, kg*1024+1024).
// B staged per-wave into wave-private 1KB frag-tiles via global_load_lds
// (slot = lane*16B, matches MFMA B-frag n=l16, k=quad*8+j; conflict-free).
// A fragments global->register, prefetched one K-step ahead; counted
// s_waitcnt vmcnt(4) leaves the 4 A-prefetch loads in flight while MFMAs
// run (B-stage glds issued first are the 4 oldest -> guaranteed drained).
// No barriers in K-loop (wave-private staging). kg-reduction in LDS (2
// rounds) + fused bias/ReLU fp16 store from kg==0 waves.
// ---------------------------------------------------------------------------
__global__ __launch_bounds__(1024) void fc1_kernel(GemmP p)
{
    __shared__ char Bs[64 * 1024];   // 64 wave-private frag-tiles of 1 KB

    const int tid = threadIdx.x;
    const int wave = tid >> 6, lane = tid & 63;
    const int l16 = lane & 15, quad = lane >> 4;
    const int kg = wave >> 2, ng = wave & 3;
    const int enc = blockIdx.y;
    const int m0 = blockIdx.x * 32;
    const int kOff = kg * 1024;
    constexpr int nsteps = 1024 / 32;   // 32

    const float* __restrict__ A = (const float*)p.A[enc];
    // per-wave B base: row = ng*64 + ni*16 + l16, col = kOff + s*32 + quad*8
    const _Float16* __restrict__ Bb =
        p.B[enc] + (size_t)(ng * 64 + l16) * NN + kOff + quad * 8;

    const size_t aoff0 = (size_t)(m0 + l16) * NN + kOff + quad * 8;
    const size_t aoff1 = aoff0 + (size_t)16 * NN;

    float4 nf0lo, nf0hi, nf1lo, nf1hi;
    auto loadA = [&](int s) {
        nf0lo = *(const float4*)(A + aoff0 + s * 32);
        nf0hi = *(const float4*)(A + aoff0 + s * 32 + 4);
        nf1lo = *(const float4*)(A + aoff1 + s * 32);
        nf1hi = *(const float4*)(A + aoff1 + s * 32 + 4);
    };

    v4f acc[2][4];
#pragma unroll
    for (int mi = 0; mi < 2; mi++)
#pragma unroll
        for (int ni = 0; ni < 4; ni++) acc[mi][ni] = (v4f){0.f, 0.f, 0.f, 0.f};

    loadA(0);

    for (int s = 0; s < nsteps; ++s) {
        // stage B(s): 4 glds issued FIRST (will be the oldest vmem ops)
#pragma unroll
        for (int ni = 0; ni < 4; ni++)
            gld_lds16(Bb + (size_t)ni * 16 * NN + s * 32, &Bs[(wave * 4 + ni) * 1024]);
        __builtin_amdgcn_sched_barrier(0);

        // consume prefetched A(s) (compiler inserts its own counted wait)
        half8 ca0, ca1;
        ca0[0] = (_Float16)nf0lo.x; ca0[1] = (_Float16)nf0lo.y;
        ca0[2] = (_Float16)nf0lo.z; ca0[3] = (_Float16)nf0lo.w;
        ca0[4] = (_Float16)nf0hi.x; ca0[5] = (_Float16)nf0hi.y;
        ca0[6] = (_Float16)nf0hi.z; ca0[7] = (_Float16)nf0hi.w;
        ca1[0] = (_Float16)nf1lo.x; ca1[1] = (_Float16)nf1lo.y;
        ca1[2] = (_Float16)nf1lo.z; ca1[3] = (_Float16)nf1lo.w;
        ca1[4] = (_Float16)nf1hi.x; ca1[5] = (_Float16)nf1hi.y;
        ca1[6] = (_Float16)nf1hi.z; ca1[7] = (_Float16)nf1hi.w;

        if (s + 1 < nsteps) {
            loadA(s + 1);   // 4 newest vmem ops: allowed to stay in flight
            __builtin_amdgcn_sched_barrier(0);
            __builtin_amdgcn_s_waitcnt(0x0F74);   // vmcnt(4): B(s) resident
        } else {
            __builtin_amdgcn_sched_barrier(0);
            __builtin_amdgcn_s_waitcnt(0x0F70);   // vmcnt(0)
        }
        __builtin_amdgcn_sched_barrier(0);

#pragma unroll
        for (int ni = 0; ni < 4; ni++) {
            half8 bf = *(const half8*)&Bs[(wave * 4 + ni) * 1024 + lane * 16];
            acc[0][ni] = __builtin_amdgcn_mfma_f32_16x16x32_f16(ca0, bf, acc[0][ni], 0, 0, 0);
            acc[1][ni] = __builtin_amdgcn_mfma_f32_16x16x32_f16(ca1, bf, acc[1][ni], 0, 0, 0);
        }
    }

    // ---- in-block kg-reduction (fp32, via LDS; Bs reused) ----------------
    __syncthreads();   // all waves done reading their frag-tiles

    // round A: kg2 -> slots 0..3, kg3 -> slots 4..7 (8 x 8KB = 64KB)
    if (kg >= 2) {
        const int sidx = (kg - 2) * 4 + ng;
#pragma unroll
        for (int mi = 0; mi < 2; mi++)
#pragma unroll
            for (int ni = 0; ni < 4; ni++)
                *(v4f*)&Bs[sidx * 8192 + (mi * 4 + ni) * 1024 + lane * 16] = acc[mi][ni];
    }
    __syncthreads();
    if (kg < 2) {
        const int sidx = kg * 4 + ng;
#pragma unroll
        for (int mi = 0; mi < 2; mi++)
#pragma unroll
            for (int ni = 0; ni < 4; ni++)
                acc[mi][ni] += *(const v4f*)&Bs[sidx * 8192 + (mi * 4 + ni) * 1024 + lane * 16];
    }
    __syncthreads();

    // round B: kg1 -> slots 0..3
    if (kg == 1) {
#pragma unroll
        for (int mi = 0; mi < 2; mi++)
#pragma unroll
            for (int ni = 0; ni < 4; ni++)
                *(v4f*)&Bs[ng * 8192 + (mi * 4 + ni) * 1024 + lane * 16] = acc[mi][ni];
    }
    __syncthreads();

    if (kg == 0) {
        _Float16* __restrict__ h1 = (_Float16*)p.C[enc];
        const float* __restrict__ bs = p.bias[enc];
#pragma unroll
        for (int mi = 0; mi < 2; mi++)
#pragma unroll
            for (int ni = 0; ni < 4; ni++) {
                v4f v = acc[mi][ni] + *(const v4f*)&Bs[ng * 8192 + (mi * 4 + ni) * 1024 + lane * 16];
                const int col = ng * 64 + ni * 16 + l16;
                const float b = bs[col];
#pragma unroll
                for (int i = 0; i < 4; i++) {
                    const int row = m0 + mi * 16 + quad * 4 + i;
                    h1[(size_t)row * 256 + col] = (_Float16)fmaxf(v[i] + b, 0.f);
                }
            }
    }
}

// ---------------------------------------------------------------------------
// MFMA GEMM (fc2/fc3): C[m,n] = act(bias[n] + sum_k A[m,k]*B[n,k])
// BM=32, BN=NI*64 (full N per block). 256 thr = 4 waves; wave w owns
// n in [w*NI*16, (w+1)*NI*16).  Unchanged from round 3.
// ---------------------------------------------------------------------------
template<int NI, bool A16, int OUT, bool RELU>
__global__ __launch_bounds__(256) void gemm_kernel(GemmP p, int M, int lda, int Ksub)
{
    constexpr int N = NI * 64;
    __shared__ char Bs[NI * 4 * 1024];   // NI*4 frag-tiles of 1 KB

    const int tid = threadIdx.x;
    const int wave = tid >> 6, lane = tid & 63;
    const int l16 = lane & 15, quad = lane >> 4;
    const int enc = blockIdx.z, split = blockIdx.x;
    const int m0 = blockIdx.y * 32;
    const int kOff = split * Ksub;
    const int nsteps = Ksub >> 5;

    const _Float16* __restrict__ Bp = p.B[enc];
    const char* Abase = (const char*)p.A[enc];

    const size_t aoff0 = (size_t)(m0 + l16) * lda + kOff + quad * 8;
    const size_t aoff1 = aoff0 + (size_t)16 * lda;

    half8 na0, na1;
    float4 nf0lo, nf0hi, nf1lo, nf1hi;
    auto loadA = [&](int s) {
        if constexpr (A16) {
            const _Float16* A = (const _Float16*)Abase;
            na0 = *(const half8*)(A + aoff0 + s * 32);
            na1 = *(const half8*)(A + aoff1 + s * 32);
        } else {
            const float* A = (const float*)Abase;
            nf0lo = *(const float4*)(A + aoff0 + s * 32);
            nf0hi = *(const float4*)(A + aoff0 + s * 32 + 4);
            nf1lo = *(const float4*)(A + aoff1 + s * 32);
            nf1hi = *(const float4*)(A + aoff1 + s * 32 + 4);
        }
    };

    v4f acc[2][NI];
#pragma unroll
    for (int mi = 0; mi < 2; mi++)
#pragma unroll
        for (int ni = 0; ni < NI; ni++) acc[mi][ni] = (v4f){0.f, 0.f, 0.f, 0.f};

    loadA(0);

    for (int s = 0; s < nsteps; ++s) {
        // stage B(s) into this wave's private frag-tiles
#pragma unroll
        for (int ni = 0; ni < NI; ni++) {
            const int T = wave * NI + ni;
            const _Float16* g = Bp + (size_t)(T * 16 + l16) * lda + kOff + s * 32 + quad * 8;
            gld_lds16(g, &Bs[T * 1024]);
        }
        // consume prefetched A(s), then prefetch A(s+1)
        half8 ca0, ca1;
        if constexpr (A16) {
            ca0 = na0; ca1 = na1;
        } else {
            ca0[0] = (_Float16)nf0lo.x; ca0[1] = (_Float16)nf0lo.y;
            ca0[2] = (_Float16)nf0lo.z; ca0[3] = (_Float16)nf0lo.w;
            ca0[4] = (_Float16)nf0hi.x; ca0[5] = (_Float16)nf0hi.y;
            ca0[6] = (_Float16)nf0hi.z; ca0[7] = (_Float16)nf0hi.w;
            ca1[0] = (_Float16)nf1lo.x; ca1[1] = (_Float16)nf1lo.y;
            ca1[2] = (_Float16)nf1lo.z; ca1[3] = (_Float16)nf1lo.w;
            ca1[4] = (_Float16)nf1hi.x; ca1[5] = (_Float16)nf1hi.y;
            ca1[6] = (_Float16)nf1hi.z; ca1[7] = (_Float16)nf1hi.w;
        }
        if (s + 1 < nsteps) loadA(s + 1);

        // wave-local drain: B(s) resident in LDS (A(s+1) also lands; fine)
        __builtin_amdgcn_s_waitcnt(0x0F70);   // vmcnt(0) only

#pragma unroll
        for (int ni = 0; ni < NI; ni++) {
            half8 bf = *(const half8*)&Bs[(wave * NI + ni) * 1024 + lane * 16];
            acc[0][ni] = __builtin_amdgcn_mfma_f32_16x16x32_f16(ca0, bf, acc[0][ni], 0, 0, 0);
            acc[1][ni] = __builtin_amdgcn_mfma_f32_16x16x32_f16(ca1, bf, acc[1][ni], 0, 0, 0);
        }
    }

    // epilogue
#pragma unroll
    for (int mi = 0; mi < 2; mi++)
#pragma unroll
        for (int ni = 0; ni < NI; ni++) {
            const int col = wave * NI * 16 + ni * 16 + l16;
#pragma unroll
            for (int i = 0; i < 4; i++) {
                const int row = m0 + mi * 16 + quad * 4 + i;
                float v = acc[mi][ni][i];
                v += p.bias[enc][col];
                if (RELU) v = fmaxf(v, 0.f);
                if constexpr (OUT == 0)
                    ((_Float16*)p.C[enc])[(size_t)row * N + col] = (_Float16)v;
                else
                    ((float*)p.C[enc])[(size_t)row * N + col] = v;
            }
        }
}

// ---------------------------------------------------------------------------
// fused fp32 -> fp16 conversion for all six weight matrices
// ---------------------------------------------------------------------------
struct CvtJob { const float* s; _Float16* d; int n4; };
struct CvtP { CvtJob j[6]; };

__global__ __launch_bounds__(256) void cvt_all_kernel(CvtP p)
{
    int i = blockIdx.x * 256 + threadIdx.x;
#pragma unroll
    for (int k = 0; k < 6; k++) {
        if (i < p.j[k].n4) {
            float4 v = ((const float4*)p.j[k].s)[i];
            half4 h;
            h[0] = (_Float16)v.x; h[1] = (_Float16)v.y;
            h[2] = (_Float16)v.z; h[3] = (_Float16)v.w;
            ((half4*)p.j[k].d)[i] = h;
            return;
        }
        i -= p.j[k].n4;
    }
}

// ---------------------------------------------------------------------------
// BatchNorm stats (two-phase, coalesced) + apply
// ---------------------------------------------------------------------------
__global__ __launch_bounds__(256) void bn_stat1_kernel(const float* __restrict__ h3,
                                                       float* __restrict__ bnp)
{
    const int enc = blockIdx.y, b = blockIdx.x;
    const int c = threadIdx.x & 63, rg = threadIdx.x >> 6;
    const float* h = h3 + (size_t)enc * ENC_OUT + (size_t)b * 128 * HDIM;
    float s = 0.f, q = 0.f;
    for (int r = rg; r < 128; r += 4) {
        float v = h[(size_t)r * HDIM + c];
        s += v; q += v * v;
    }
    __shared__ float ss[4][64], sq[4][64];
    ss[rg][c] = s; sq[rg][c] = q;
    __syncthreads();
    if (threadIdx.x < 64) {
        float S = ss[0][c] + ss[1][c] + ss[2][c] + ss[3][c];
        float Q = sq[0][c] + sq[1][c] + sq[2][c] + sq[3][c];
        bnp[(size_t)(enc * 32 + b) * 128 + c] = S;
        bnp[(size_t)(enc * 32 + b) * 128 + 64 + c] = Q;
    }
}

__global__ void bn_stat2_kernel(const float* __restrict__ bnp, float* __restrict__ stats)
{
    const int enc = blockIdx.x, c = threadIdx.x;  // 64 threads
    float s = 0.f, q = 0.f;
    for (int b = 0; b < 32; b++) {
        s += bnp[(size_t)(enc * 32 + b) * 128 + c];
        q += bnp[(size_t)(enc * 32 + b) * 128 + 64 + c];
    }
    float mean = s * (1.f / NN);
    float var = q * (1.f / NN) - mean * mean;
    stats[enc * 128 + c] = mean;
    stats[enc * 128 + 64 + c] = rsqrtf(var + 1e-5f);
}

__global__ __launch_bounds__(256) void bn_apply_kernel(const float* __restrict__ h3,
                                                       const float* __restrict__ stats,
                                                       const float* __restrict__ g0,
                                                       const float* __restrict__ g1,
                                                       const float* __restrict__ be0,
                                                       const float* __restrict__ be1,
                                                       float* __restrict__ hn)
{
    const int idx = blockIdx.x * 256 + threadIdx.x;
    const int enc = idx >> 18;
    const int c = idx & 63;
    const float* g = enc ? g1 : g0;
    const float* be = enc ? be1 : be0;
    const float m = stats[enc * 128 + c];
    const float rs = stats[enc * 128 + 64 + c];
    float v = (h3[idx] - m) * rs * g[c] + be[c];
    hn[idx] = fmaxf(v, 0.f);
}

// ---------------------------------------------------------------------------
// Self-attention: masked mean over ~41 neighbors + residual.
// ---------------------------------------------------------------------------
__global__ __launch_bounds__(256) void att_kernel(const float* __restrict__ adj1,
                                                  const float* __restrict__ adj2,
                                                  const float* __restrict__ al1,
                                                  const float* __restrict__ al2,
                                                  const float* __restrict__ hn,
                                                  float* __restrict__ out)
{
    const int enc = blockIdx.y;
    const float* adj = enc ? adj2 : adj1;
    const float* al = enc ? al2 : al1;
    const float* h = hn + (size_t)enc * ENC_OUT;
    float* o = out + (size_t)enc * ENC_OUT;
    const int i = blockIdx.x;
    const int tid = threadIdx.x;

    __shared__ int s_cnt;
    __shared__ int s_j[128];
    __shared__ float s_w[128];
    __shared__ float s_acc[4][64];

    if (tid == 0) s_cnt = 0;
    __syncthreads();

    const float* arow = adj + (size_t)i * NN;
    const int jb = tid * 16;
#pragma unroll
    for (int q = 0; q < 4; q++) {
        float4 a = *(const float4*)&arow[jb + q * 4];
        if (a.x == 1.f) { int p = atomicAdd(&s_cnt, 1); if (p < 128) s_j[p] = jb + q * 4 + 0; }
        if (a.y == 1.f) { int p = atomicAdd(&s_cnt, 1); if (p < 128) s_j[p] = jb + q * 4 + 1; }
        if (a.z == 1.f) { int p = atomicAdd(&s_cnt, 1); if (p < 128) s_j[p] = jb + q * 4 + 2; }
        if (a.w == 1.f) { int p = atomicAdd(&s_cnt, 1); if (p < 128) s_j[p] = jb + q * 4 + 3; }
    }
    __syncthreads();
    const int cnt = min(s_cnt, 128);

    const float* alrow = al + (size_t)i * NN;
    for (int t = tid; t < cnt; t += 256) s_w[t] = alrow[s_j[t]];
    __syncthreads();

    const int c = tid & 63;
    const int g = tid >> 6;
    float acc = 0.f;
    for (int t = g; t < cnt; t += 4) acc += s_w[t] * h[(size_t)s_j[t] * HDIM + c];
    s_acc[g][c] = acc;
    __syncthreads();

    if (tid < 64) {
        float r;
        if (cnt != 0) {
            r = (s_acc[0][c] + s_acc[1][c] + s_acc[2][c] + s_acc[3][c]) / (float)cnt
                + h[(size_t)i * HDIM + c];
        } else {
            r = 0.f;
        }
        o[(size_t)i * HDIM + c] = r;
    }
}

// ---------------------------------------------------------------------------
// Head: 512-block two-phase reduction
// ---------------------------------------------------------------------------
#define FDIM (2 * ENC_OUT)

__global__ __launch_bounds__(256) void final_partial_kernel(const float* __restrict__ feat,
                                                            const float* __restrict__ Wc,
                                                            float* __restrict__ partial)
{
    const int gt = blockIdx.x * 256 + threadIdx.x;   // 131072 threads
    float p0 = 0.f, p1 = 0.f;
    for (int f = gt; f < FDIM; f += 131072) {
        float x = feat[f];
        p0 += x * Wc[f];
        p1 += x * Wc[FDIM + f];
    }
    __shared__ float r0[256], r1[256];
    r0[threadIdx.x] = p0;
    r1[threadIdx.x] = p1;
    __syncthreads();
    for (int off = 128; off > 0; off >>= 1) {
        if (threadIdx.x < off) {
            r0[threadIdx.x] += r0[threadIdx.x + off];
            r1[threadIdx.x] += r1[threadIdx.x + off];
        }
        __syncthreads();
    }
    if (threadIdx.x == 0) {
        partial[blockIdx.x * 2 + 0] = r0[0];
        partial[blockIdx.x * 2 + 1] = r1[0];
    }
}

__global__ void final_reduce_kernel(const float* __restrict__ partial,
                                    const float* __restrict__ bc,
                                    float* __restrict__ out)
{
    const int t = threadIdx.x;
    if (t < 2) {
        float s = bc[t];
        for (int b = 0; b < 512; b++) s += partial[b * 2 + t];
        out[t] = s;
    }
}

// ---------------------------------------------------------------------------

extern "C" void kernel_launch(void* const* d_in, const int* in_sizes, int n_in,
                              void* d_out, int out_size, void* d_ws, size_t ws_size,
                              hipStream_t stream)
{
    const float* x1    = (const float*)d_in[0];
    const float* x2    = (const float*)d_in[1];
    const float* adj1  = (const float*)d_in[2];
    const float* adj2  = (const float*)d_in[3];
    const float* e1_W1 = (const float*)d_in[4];
    const float* e1_b1 = (const float*)d_in[5];
    const float* e1_W2 = (const float*)d_in[6];
    const float* e1_b2 = (const float*)d_in[7];
    const float* e1_W3 = (const float*)d_in[8];
    const float* e1_b3 = (const float*)d_in[9];
    const float* e1_g  = (const float*)d_in[10];
    const float* e1_be = (const float*)d_in[11];
    const float* e2_W1 = (const float*)d_in[12];
    const float* e2_b1 = (const float*)d_in[13];
    const float* e2_W2 = (const float*)d_in[14];
    const float* e2_b2 = (const float*)d_in[15];
    const float* e2_W3 = (const float*)d_in[16];
    const float* e2_b3 = (const float*)d_in[17];
    const float* e2_g  = (const float*)d_in[18];
    const float* e2_be = (const float*)d_in[19];
    const float* alpha1 = (const float*)d_in[20];
    const float* alpha2 = (const float*)d_in[21];
    const float* Wc    = (const float*)d_in[22];
    const float* bc    = (const float*)d_in[23];
    (void)in_sizes; (void)n_in; (void)out_size; (void)ws_size;

    // ---- workspace layout (~17.0 MB) -------------------------------------
    char* w = (char*)d_ws;
    _Float16* W1h = (_Float16*)w;  w += (size_t)2 * 256 * NN * 2;      // 4 MB
    _Float16* W2h = (_Float16*)w;  w += (size_t)2 * 128 * 256 * 2;     // 128 KB
    _Float16* W3h = (_Float16*)w;  w += (size_t)2 * 64 * 128 * 2;      // 32 KB
    _Float16* h1h = (_Float16*)w;  w += (size_t)2 * NN * 256 * 2;      // 4 MB
    char* shared8 = w;             w += (size_t)8 * 1024 * 1024;       // 8 MB
    float* bnp = (float*)w;        w += (size_t)2 * 32 * 128 * 4;      // 32 KB
    float* stats = (float*)w;      w += 256 * 4;
    float* hpart = (float*)w;      w += 1024 * 4;

    _Float16* h2h  = (_Float16*)shared8;                 // 2 MB
    float* h3  = (float*)(shared8 + 2 * 1024 * 1024);    // 2 MB
    float* hn  = (float*)(shared8 + 4 * 1024 * 1024);    // 2 MB
    float* att = (float*)(shared8 + 6 * 1024 * 1024);    // 2 MB

    const dim3 blk(256);

    // ---- weight conversion (single fused kernel) -------------------------
    CvtP cp;
    cp.j[0] = { e1_W1, W1h,             262144 };
    cp.j[1] = { e2_W1, W1h + 256 * NN,  262144 };
    cp.j[2] = { e1_W2, W2h,             8192 };
    cp.j[3] = { e2_W2, W2h + 128 * 256, 8192 };
    cp.j[4] = { e1_W3, W3h,             2048 };
    cp.j[5] = { e2_W3, W3h + 64 * 128,  2048 };
    cvt_all_kernel<<<dim3(2128), blk, 0, stream>>>(cp);

    // ---- fc1: [4096,4096] -> 256, in-block split-K x4, fused bias+ReLU ---
    GemmP p1 = { {x1, x2}, {W1h, W1h + 256 * NN}, {e1_b1, e2_b1},
                 {h1h, h1h + (size_t)NN * 256} };
    fc1_kernel<<<dim3(NN / 32, 2), dim3(1024), 0, stream>>>(p1);

    // ---- fc2: [4096,256] -> 128, ReLU, fp16 out --------------------------
    GemmP p2 = { {h1h, h1h + (size_t)NN * 256}, {W2h, W2h + 128 * 256}, {e1_b2, e2_b2},
                 {h2h, h2h + (size_t)NN * 128} };
    gemm_kernel<2, true, 0, true><<<dim3(1, NN / 32, 2), blk, 0, stream>>>(p2, NN, 256, 256);

    // ---- fc3: [4096,128] -> 64, fp32 out (BN follows) --------------------
    GemmP p3 = { {h2h, h2h + (size_t)NN * 128}, {W3h, W3h + 64 * 128}, {e1_b3, e2_b3},
                 {h3, h3 + ENC_OUT} };
    gemm_kernel<1, true, 1, false><<<dim3(1, NN / 32, 2), blk, 0, stream>>>(p3, NN, 128, 128);

    // ---- BatchNorm (train-mode) + ReLU -----------------------------------
    bn_stat1_kernel<<<dim3(32, 2), blk, 0, stream>>>(h3, bnp);
    bn_stat2_kernel<<<dim3(2), dim3(64), 0, stream>>>(bnp, stats);
    bn_apply_kernel<<<dim3(2 * ENC_OUT / 256), blk, 0, stream>>>(h3, stats, e1_g, e2_g,
                                                                 e1_be, e2_be, hn);

    // ---- self-attention --------------------------------------------------
    att_kernel<<<dim3(NN, 2), blk, 0, stream>>>(adj1, adj2, alpha1, alpha2, hn, att);

    // ---- head ------------------------------------------------------------
    final_partial_kernel<<<dim3(512), blk, 0, stream>>>(att, Wc, hpart);
    final_reduce_kernel<<<dim3(1), dim3(64), 0, stream>>>(hpart, bc, (float*)d_out);
}

// Round 2
// 469.759 us; speedup vs baseline: 1.0869x; 1.0782x over previous
//
#include <hip/hip_runtime.h>
#include <cstddef>
#include <cstdint>

// ---------------------------------------------------------------------------
// GraphClassifier round 5.
// fc1 rebuilt around the measured per-CU vmem request-rate bound:
//  - A staged once per kg-group via ONE full-line glds per wave per step
//    (XOR-pre-swizzled global source -> linear LDS dest, conflict-free reads)
//  - cooperative fp32->fp16 cvt in LDS (cvt once, not once per consumer)
//  - B weight fragments global->register (full-line, frag-ordered), s+1
//    prefetch
//  - raw s_barrier + counted vmcnt(5): loads stay in flight across barriers
// final_reduce parallelized (was 2 threads x 512 serial loads).
// fc2/fc3/BN/attention unchanged.
// ---------------------------------------------------------------------------

#define NN 4096
#define HDIM 64
#define ENC_OUT (NN * HDIM)   // 262144 = 2^18

typedef _Float16 half8 __attribute__((ext_vector_type(8)));
typedef _Float16 half4 __attribute__((ext_vector_type(4)));
typedef float v4f __attribute__((ext_vector_type(4)));

__device__ __forceinline__ void gld_lds16(const void* g, void* l) {
    __builtin_amdgcn_global_load_lds(
        (const __attribute__((address_space(1))) void*)g,
        (__attribute__((address_space(3))) void*)l, 16, 0, 0);
}

struct GemmP {
    const void*     A[2];     // fp32 (fc1) or fp16, row-major [M,lda]
    const _Float16* B[2];     // weight fp16, row-major [N,lda]
    const float*    bias[2];
    void*           C[2];     // OUT=0: fp16 per-enc; OUT=1: fp32 per-enc
};

// ---------------------------------------------------------------------------
// fc1: C[m,n] = relu(bias[n] + sum_k A[m,k]*B[n,k]),  M=4096 N=256 K=4096.
// Block: 1024 thr = 16 waves, wave w -> (kg=w>>2, ng=w&3), BM=32.
// Per step (BK=32):
//   fp32 A tile [32x32] per kg staged by the 4 ng-waves (1 glds each, 8 rows
//   x 128B full lines, XOR-swizzled source so linear LDS dest is readable
//   conflict-free), double-buffered.
//   Each wave cvts its OWN staged quarter fp32->fp16 into a shared fp16 tile
//   ([4 chunk-groups][32 rows][16B], double-buffered) -> consumers read their
//   MFMA A-frag as ONE contiguous ds_read_b128, no cvt.
//   B frags load straight to registers (frag order: row=l16, k=quad*8+j;
//   16 full 64B lines per instr), prefetched one step ahead.
// One raw s_barrier per step; counted s_waitcnt vmcnt(5) keeps B(s+1) and
// fp32A(s+2) in flight across it. kg-reduction in LDS + bias/ReLU epilogue.
// ---------------------------------------------------------------------------
__global__ __launch_bounds__(1024, 4) void fc1_kernel(GemmP p)
{
    __shared__ char lds[64 * 1024];
    // in-loop: fp32 tiles [kg][buf2][4KB] at 0      (32 KB)
    //          fp16 tiles [kg][buf2][2KB] at 32768  (16 KB)
    // epilogue reduction reuses all 64 KB.

    const int tid = threadIdx.x;
    const int wave = tid >> 6, lane = tid & 63;
    const int l16 = lane & 15, quad = lane >> 4;
    const int kg = wave >> 2, ng = wave & 3;
    const int enc = blockIdx.y;
    const int m0 = blockIdx.x * 32;
    const int kOff = kg * 1024;
    constexpr int NS = 32;

    const float* __restrict__ A = (const float*)p.A[enc];
    const _Float16* __restrict__ Bp = p.B[enc];

    // ---- A staging: this wave's glds covers rows ng*8..ng*8+8 ------------
    // LDS position p = ng*64 + lane (16B units); row = p>>3, stored chunk
    // c_stored = lane&7, actual chunk c = c_stored ^ (row&7).
    const int srow = ng * 8 + (lane >> 3);
    const int schunk = (lane & 7) ^ ((lane >> 3) & 7);
    const float* asrc0 = A + (size_t)(m0 + srow) * NN + kOff + schunk * 4;
    char* f32base = &lds[kg * 8192 + ng * 1024];      // + buf*4096 (+lane*16)
    char* f16kg   = &lds[32768 + kg * 4096];          // + buf*2048

    // cvt-phase: lane re-reads its own staged 16B (4 floats, k = schunk*4..+4)
    // and writes 8B into fp16 tile [cq][row][16B] at half = schunk&1.
    const int f16woff = (schunk >> 1) * 512 + srow * 16 + (schunk & 1) * 8;

    // consumer frag offsets: mi row = mi*16+l16, chunk-group = quad
    const int frag0 = quad * 512 + l16 * 16;
    const int frag1 = quad * 512 + (16 + l16) * 16;

    // ---- B fragment source (registers, frag order) -----------------------
    const _Float16* bsrc = Bp + (size_t)(ng * 64 + l16) * NN + kOff + quad * 8;

    v4f acc[2][4];
#pragma unroll
    for (int mi = 0; mi < 2; mi++)
#pragma unroll
        for (int ni = 0; ni < 4; ni++) acc[mi][ni] = (v4f){0.f, 0.f, 0.f, 0.f};

    half8 b0[4], b1[4];

    // ---- prologue: A(0), B(0), A(1); cvt A(0) ----------------------------
    gld_lds16(asrc0, f32base);                        // f32(0) -> buf0
#pragma unroll
    for (int ni = 0; ni < 4; ni++)
        b0[ni] = *(const half8*)(bsrc + (size_t)ni * 16 * NN);
    gld_lds16(asrc0 + 32, f32base + 4096);            // f32(1) -> buf1
    __builtin_amdgcn_sched_barrier(0);
    __builtin_amdgcn_s_waitcnt(0x0F75);               // drain f32(0) only
    __builtin_amdgcn_sched_barrier(0);
    {
        float4 f = *(const float4*)(f32base + lane * 16);
        half4 h;
        h[0] = (_Float16)f.x; h[1] = (_Float16)f.y;
        h[2] = (_Float16)f.z; h[3] = (_Float16)f.w;
        *(half4*)(f16kg + f16woff) = h;               // fp16(0) -> buf0
    }
    __builtin_amdgcn_sched_barrier(0);
    __builtin_amdgcn_s_waitcnt(0x3F7F & 0xC07F);      // lgkmcnt(0)
    __builtin_amdgcn_sched_barrier(0);
    __builtin_amdgcn_s_barrier();                     // publish fp16(0)

    auto body = [&](int s, half8* bcur, half8* bnxt) {
        // 1. prefetch B(s+1) -> regs
        if (s + 1 < NS) {
#pragma unroll
            for (int ni = 0; ni < 4; ni++)
                bnxt[ni] = *(const half8*)(bsrc + (size_t)ni * 16 * NN + (s + 1) * 32);
        }
        // 2. stage fp32 A(s+2)
        if (s + 2 < NS)
            gld_lds16(asrc0 + (s + 2) * 32, f32base + ((s + 2) & 1) * 4096);
        __builtin_amdgcn_sched_barrier(0);
        // 3. counted drain: B(s) + f32(s+1) resident; newer loads in flight
        if (s + 2 < NS)      __builtin_amdgcn_s_waitcnt(0x0F75);  // vmcnt(5)
        else if (s + 1 < NS) __builtin_amdgcn_s_waitcnt(0x0F74);  // vmcnt(4)
        else                 __builtin_amdgcn_s_waitcnt(0x0F70);  // vmcnt(0)
        __builtin_amdgcn_sched_barrier(0);
        // 4. cvt own quarter of fp32(s+1) -> fp16 tile (s+1)
        if (s + 1 < NS) {
            float4 f = *(const float4*)(f32base + ((s + 1) & 1) * 4096 + lane * 16);
            half4 h;
            h[0] = (_Float16)f.x; h[1] = (_Float16)f.y;
            h[2] = (_Float16)f.z; h[3] = (_Float16)f.w;
            *(half4*)(f16kg + ((s + 1) & 1) * 2048 + f16woff) = h;
        }
        // 5. consume fp16(s): one b128 per mi-frag, then MFMA
        const char* fb = f16kg + (s & 1) * 2048;
        half8 ca0 = *(const half8*)(fb + frag0);
        half8 ca1 = *(const half8*)(fb + frag1);
#pragma unroll
        for (int ni = 0; ni < 4; ni++) {
            acc[0][ni] = __builtin_amdgcn_mfma_f32_16x16x32_f16(ca0, bcur[ni], acc[0][ni], 0, 0, 0);
            acc[1][ni] = __builtin_amdgcn_mfma_f32_16x16x32_f16(ca1, bcur[ni], acc[1][ni], 0, 0, 0);
        }
        // 6-7. drain own ds ops, publish fp16(s+1)
        __builtin_amdgcn_sched_barrier(0);
        __builtin_amdgcn_s_waitcnt(0xC07F);           // lgkmcnt(0)
        __builtin_amdgcn_sched_barrier(0);
        __builtin_amdgcn_s_barrier();
    };

    for (int s = 0; s < NS; s += 2) {
        body(s, b0, b1);
        body(s + 1, b1, b0);
    }

    // ---- in-block kg-reduction (fp32, via LDS) ---------------------------
    __syncthreads();

    if (kg >= 2) {
        const int sidx = (kg - 2) * 4 + ng;
#pragma unroll
        for (int mi = 0; mi < 2; mi++)
#pragma unroll
            for (int ni = 0; ni < 4; ni++)
                *(v4f*)&lds[sidx * 8192 + (mi * 4 + ni) * 1024 + lane * 16] = acc[mi][ni];
    }
    __syncthreads();
    if (kg < 2) {
        const int sidx = kg * 4 + ng;
#pragma unroll
        for (int mi = 0; mi < 2; mi++)
#pragma unroll
            for (int ni = 0; ni < 4; ni++)
                acc[mi][ni] += *(const v4f*)&lds[sidx * 8192 + (mi * 4 + ni) * 1024 + lane * 16];
    }
    __syncthreads();

    if (kg == 1) {
#pragma unroll
        for (int mi = 0; mi < 2; mi++)
#pragma unroll
            for (int ni = 0; ni < 4; ni++)
                *(v4f*)&lds[ng * 8192 + (mi * 4 + ni) * 1024 + lane * 16] = acc[mi][ni];
    }
    __syncthreads();

    if (kg == 0) {
        _Float16* __restrict__ h1 = (_Float16*)p.C[enc];
        const float* __restrict__ bs = p.bias[enc];
#pragma unroll
        for (int mi = 0; mi < 2; mi++)
#pragma unroll
            for (int ni = 0; ni < 4; ni++) {
                v4f v = acc[mi][ni] + *(const v4f*)&lds[ng * 8192 + (mi * 4 + ni) * 1024 + lane * 16];
                const int col = ng * 64 + ni * 16 + l16;
                const float b = bs[col];
#pragma unroll
                for (int i = 0; i < 4; i++) {
                    const int row = m0 + mi * 16 + quad * 4 + i;
                    h1[(size_t)row * 256 + col] = (_Float16)fmaxf(v[i] + b, 0.f);
                }
            }
    }
}

// ---------------------------------------------------------------------------
// MFMA GEMM (fc2/fc3): C[m,n] = act(bias[n] + sum_k A[m,k]*B[n,k])
// BM=32, BN=NI*64 (full N per block). 256 thr = 4 waves.
// ---------------------------------------------------------------------------
template<int NI, bool A16, int OUT, bool RELU>
__global__ __launch_bounds__(256) void gemm_kernel(GemmP p, int M, int lda, int Ksub)
{
    constexpr int N = NI * 64;
    __shared__ char Bs[NI * 4 * 1024];   // NI*4 frag-tiles of 1 KB

    const int tid = threadIdx.x;
    const int wave = tid >> 6, lane = tid & 63;
    const int l16 = lane & 15, quad = lane >> 4;
    const int enc = blockIdx.z, split = blockIdx.x;
    const int m0 = blockIdx.y * 32;
    const int kOff = split * Ksub;
    const int nsteps = Ksub >> 5;

    const _Float16* __restrict__ Bp = p.B[enc];
    const char* Abase = (const char*)p.A[enc];

    const size_t aoff0 = (size_t)(m0 + l16) * lda + kOff + quad * 8;
    const size_t aoff1 = aoff0 + (size_t)16 * lda;

    half8 na0, na1;
    float4 nf0lo, nf0hi, nf1lo, nf1hi;
    auto loadA = [&](int s) {
        if constexpr (A16) {
            const _Float16* A = (const _Float16*)Abase;
            na0 = *(const half8*)(A + aoff0 + s * 32);
            na1 = *(const half8*)(A + aoff1 + s * 32);
        } else {
            const float* A = (const float*)Abase;
            nf0lo = *(const float4*)(A + aoff0 + s * 32);
            nf0hi = *(const float4*)(A + aoff0 + s * 32 + 4);
            nf1lo = *(const float4*)(A + aoff1 + s * 32);
            nf1hi = *(const float4*)(A + aoff1 + s * 32 + 4);
        }
    };

    v4f acc[2][NI];
#pragma unroll
    for (int mi = 0; mi < 2; mi++)
#pragma unroll
        for (int ni = 0; ni < NI; ni++) acc[mi][ni] = (v4f){0.f, 0.f, 0.f, 0.f};

    loadA(0);

    for (int s = 0; s < nsteps; ++s) {
#pragma unroll
        for (int ni = 0; ni < NI; ni++) {
            const int T = wave * NI + ni;
            const _Float16* g = Bp + (size_t)(T * 16 + l16) * lda + kOff + s * 32 + quad * 8;
            gld_lds16(g, &Bs[T * 1024]);
        }
        half8 ca0, ca1;
        if constexpr (A16) {
            ca0 = na0; ca1 = na1;
        } else {
            ca0[0] = (_Float16)nf0lo.x; ca0[1] = (_Float16)nf0lo.y;
            ca0[2] = (_Float16)nf0lo.z; ca0[3] = (_Float16)nf0lo.w;
            ca0[4] = (_Float16)nf0hi.x; ca0[5] = (_Float16)nf0hi.y;
            ca0[6] = (_Float16)nf0hi.z; ca0[7] = (_Float16)nf0hi.w;
            ca1[0] = (_Float16)nf1lo.x; ca1[1] = (_Float16)nf1lo.y;
            ca1[2] = (_Float16)nf1lo.z; ca1[3] = (_Float16)nf1lo.w;
            ca1[4] = (_Float16)nf1hi.x; ca1[5] = (_Float16)nf1hi.y;
            ca1[6] = (_Float16)nf1hi.z; ca1[7] = (_Float16)nf1hi.w;
        }
        if (s + 1 < nsteps) loadA(s + 1);

        __builtin_amdgcn_s_waitcnt(0x0F70);   // vmcnt(0) only

#pragma unroll
        for (int ni = 0; ni < NI; ni++) {
            half8 bf = *(const half8*)&Bs[(wave * NI + ni) * 1024 + lane * 16];
            acc[0][ni] = __builtin_amdgcn_mfma_f32_16x16x32_f16(ca0, bf, acc[0][ni], 0, 0, 0);
            acc[1][ni] = __builtin_amdgcn_mfma_f32_16x16x32_f16(ca1, bf, acc[1][ni], 0, 0, 0);
        }
    }

#pragma unroll
    for (int mi = 0; mi < 2; mi++)
#pragma unroll
        for (int ni = 0; ni < NI; ni++) {
            const int col = wave * NI * 16 + ni * 16 + l16;
#pragma unroll
            for (int i = 0; i < 4; i++) {
                const int row = m0 + mi * 16 + quad * 4 + i;
                float v = acc[mi][ni][i];
                v += p.bias[enc][col];
                if (RELU) v = fmaxf(v, 0.f);
                if constexpr (OUT == 0)
                    ((_Float16*)p.C[enc])[(size_t)row * N + col] = (_Float16)v;
                else
                    ((float*)p.C[enc])[(size_t)row * N + col] = v;
            }
        }
}

// ---------------------------------------------------------------------------
// fused fp32 -> fp16 conversion for all six weight matrices
// ---------------------------------------------------------------------------
struct CvtJob { const float* s; _Float16* d; int n4; };
struct CvtP { CvtJob j[6]; };

__global__ __launch_bounds__(256) void cvt_all_kernel(CvtP p)
{
    int i = blockIdx.x * 256 + threadIdx.x;
#pragma unroll
    for (int k = 0; k < 6; k++) {
        if (i < p.j[k].n4) {
            float4 v = ((const float4*)p.j[k].s)[i];
            half4 h;
            h[0] = (_Float16)v.x; h[1] = (_Float16)v.y;
            h[2] = (_Float16)v.z; h[3] = (_Float16)v.w;
            ((half4*)p.j[k].d)[i] = h;
            return;
        }
        i -= p.j[k].n4;
    }
}

// ---------------------------------------------------------------------------
// BatchNorm stats (two-phase, coalesced) + apply
// ---------------------------------------------------------------------------
__global__ __launch_bounds__(256) void bn_stat1_kernel(const float* __restrict__ h3,
                                                       float* __restrict__ bnp)
{
    const int enc = blockIdx.y, b = blockIdx.x;
    const int c = threadIdx.x & 63, rg = threadIdx.x >> 6;
    const float* h = h3 + (size_t)enc * ENC_OUT + (size_t)b * 128 * HDIM;
    float s = 0.f, q = 0.f;
    for (int r = rg; r < 128; r += 4) {
        float v = h[(size_t)r * HDIM + c];
        s += v; q += v * v;
    }
    __shared__ float ss[4][64], sq[4][64];
    ss[rg][c] = s; sq[rg][c] = q;
    __syncthreads();
    if (threadIdx.x < 64) {
        float S = ss[0][c] + ss[1][c] + ss[2][c] + ss[3][c];
        float Q = sq[0][c] + sq[1][c] + sq[2][c] + sq[3][c];
        bnp[(size_t)(enc * 32 + b) * 128 + c] = S;
        bnp[(size_t)(enc * 32 + b) * 128 + 64 + c] = Q;
    }
}

__global__ void bn_stat2_kernel(const float* __restrict__ bnp, float* __restrict__ stats)
{
    const int enc = blockIdx.x, c = threadIdx.x;  // 64 threads
    float s = 0.f, q = 0.f;
    for (int b = 0; b < 32; b++) {
        s += bnp[(size_t)(enc * 32 + b) * 128 + c];
        q += bnp[(size_t)(enc * 32 + b) * 128 + 64 + c];
    }
    float mean = s * (1.f / NN);
    float var = q * (1.f / NN) - mean * mean;
    stats[enc * 128 + c] = mean;
    stats[enc * 128 + 64 + c] = rsqrtf(var + 1e-5f);
}

__global__ __launch_bounds__(256) void bn_apply_kernel(const float* __restrict__ h3,
                                                       const float* __restrict__ stats,
                                                       const float* __restrict__ g0,
                                                       const float* __restrict__ g1,
                                                       const float* __restrict__ be0,
                                                       const float* __restrict__ be1,
                                                       float* __restrict__ hn)
{
    const int idx = blockIdx.x * 256 + threadIdx.x;
    const int enc = idx >> 18;
    const int c = idx & 63;
    const float* g = enc ? g1 : g0;
    const float* be = enc ? be1 : be0;
    const float m = stats[enc * 128 + c];
    const float rs = stats[enc * 128 + 64 + c];
    float v = (h3[idx] - m) * rs * g[c] + be[c];
    hn[idx] = fmaxf(v, 0.f);
}

// ---------------------------------------------------------------------------
// Self-attention: masked mean over ~41 neighbors + residual.
// ---------------------------------------------------------------------------
__global__ __launch_bounds__(256) void att_kernel(const float* __restrict__ adj1,
                                                  const float* __restrict__ adj2,
                                                  const float* __restrict__ al1,
                                                  const float* __restrict__ al2,
                                                  const float* __restrict__ hn,
                                                  float* __restrict__ out)
{
    const int enc = blockIdx.y;
    const float* adj = enc ? adj2 : adj1;
    const float* al = enc ? al2 : al1;
    const float* h = hn + (size_t)enc * ENC_OUT;
    float* o = out + (size_t)enc * ENC_OUT;
    const int i = blockIdx.x;
    const int tid = threadIdx.x;

    __shared__ int s_cnt;
    __shared__ int s_j[128];
    __shared__ float s_w[128];
    __shared__ float s_acc[4][64];

    if (tid == 0) s_cnt = 0;
    __syncthreads();

    const float* arow = adj + (size_t)i * NN;
    const int jb = tid * 16;
#pragma unroll
    for (int q = 0; q < 4; q++) {
        float4 a = *(const float4*)&arow[jb + q * 4];
        if (a.x == 1.f) { int p = atomicAdd(&s_cnt, 1); if (p < 128) s_j[p] = jb + q * 4 + 0; }
        if (a.y == 1.f) { int p = atomicAdd(&s_cnt, 1); if (p < 128) s_j[p] = jb + q * 4 + 1; }
        if (a.z == 1.f) { int p = atomicAdd(&s_cnt, 1); if (p < 128) s_j[p] = jb + q * 4 + 2; }
        if (a.w == 1.f) { int p = atomicAdd(&s_cnt, 1); if (p < 128) s_j[p] = jb + q * 4 + 3; }
    }
    __syncthreads();
    const int cnt = min(s_cnt, 128);

    const float* alrow = al + (size_t)i * NN;
    for (int t = tid; t < cnt; t += 256) s_w[t] = alrow[s_j[t]];
    __syncthreads();

    const int c = tid & 63;
    const int g = tid >> 6;
    float acc = 0.f;
    for (int t = g; t < cnt; t += 4) acc += s_w[t] * h[(size_t)s_j[t] * HDIM + c];
    s_acc[g][c] = acc;
    __syncthreads();

    if (tid < 64) {
        float r;
        if (cnt != 0) {
            r = (s_acc[0][c] + s_acc[1][c] + s_acc[2][c] + s_acc[3][c]) / (float)cnt
                + h[(size_t)i * HDIM + c];
        } else {
            r = 0.f;
        }
        o[(size_t)i * HDIM + c] = r;
    }
}

// ---------------------------------------------------------------------------
// Head: 512-block two-phase reduction
// ---------------------------------------------------------------------------
#define FDIM (2 * ENC_OUT)

__global__ __launch_bounds__(256) void final_partial_kernel(const float* __restrict__ feat,
                                                            const float* __restrict__ Wc,
                                                            float* __restrict__ partial)
{
    const int gt = blockIdx.x * 256 + threadIdx.x;   // 131072 threads
    float p0 = 0.f, p1 = 0.f;
    for (int f = gt; f < FDIM; f += 131072) {
        float x = feat[f];
        p0 += x * Wc[f];
        p1 += x * Wc[FDIM + f];
    }
    __shared__ float r0[256], r1[256];
    r0[threadIdx.x] = p0;
    r1[threadIdx.x] = p1;
    __syncthreads();
    for (int off = 128; off > 0; off >>= 1) {
        if (threadIdx.x < off) {
            r0[threadIdx.x] += r0[threadIdx.x + off];
            r1[threadIdx.x] += r1[threadIdx.x + off];
        }
        __syncthreads();
    }
    if (threadIdx.x == 0) {
        partial[blockIdx.x * 2 + 0] = r0[0];
        partial[blockIdx.x * 2 + 1] = r1[0];
    }
}

__global__ __launch_bounds__(256) void final_reduce_kernel(const float* __restrict__ partial,
                                                           const float* __restrict__ bc,
                                                           float* __restrict__ out)
{
    // partial: 512 x 2 floats interleaved; 256 threads, 2 float2 each
    const int t = threadIdx.x;
    float2 v = ((const float2*)partial)[t];
    float2 w = ((const float2*)partial)[t + 256];
    __shared__ float r0[256], r1[256];
    r0[t] = v.x + w.x;
    r1[t] = v.y + w.y;
    __syncthreads();
    for (int off = 128; off > 0; off >>= 1) {
        if (t < off) {
            r0[t] += r0[t + off];
            r1[t] += r1[t + off];
        }
        __syncthreads();
    }
    if (t == 0) {
        out[0] = bc[0] + r0[0];
        out[1] = bc[1] + r1[0];
    }
}

// ---------------------------------------------------------------------------

extern "C" void kernel_launch(void* const* d_in, const int* in_sizes, int n_in,
                              void* d_out, int out_size, void* d_ws, size_t ws_size,
                              hipStream_t stream)
{
    const float* x1    = (const float*)d_in[0];
    const float* x2    = (const float*)d_in[1];
    const float* adj1  = (const float*)d_in[2];
    const float* adj2  = (const float*)d_in[3];
    const float* e1_W1 = (const float*)d_in[4];
    const float* e1_b1 = (const float*)d_in[5];
    const float* e1_W2 = (const float*)d_in[6];
    const float* e1_b2 = (const float*)d_in[7];
    const float* e1_W3 = (const float*)d_in[8];
    const float* e1_b3 = (const float*)d_in[9];
    const float* e1_g  = (const float*)d_in[10];
    const float* e1_be = (const float*)d_in[11];
    const float* e2_W1 = (const float*)d_in[12];
    const float* e2_b1 = (const float*)d_in[13];
    const float* e2_W2 = (const float*)d_in[14];
    const float* e2_b2 = (const float*)d_in[15];
    const float* e2_W3 = (const float*)d_in[16];
    const float* e2_b3 = (const float*)d_in[17];
    const float* e2_g  = (const float*)d_in[18];
    const float* e2_be = (const float*)d_in[19];
    const float* alpha1 = (const float*)d_in[20];
    const float* alpha2 = (const float*)d_in[21];
    const float* Wc    = (const float*)d_in[22];
    const float* bc    = (const float*)d_in[23];
    (void)in_sizes; (void)n_in; (void)out_size; (void)ws_size;

    // ---- workspace layout (~17.0 MB) -------------------------------------
    char* w = (char*)d_ws;
    _Float16* W1h = (_Float16*)w;  w += (size_t)2 * 256 * NN * 2;      // 4 MB
    _Float16* W2h = (_Float16*)w;  w += (size_t)2 * 128 * 256 * 2;     // 128 KB
    _Float16* W3h = (_Float16*)w;  w += (size_t)2 * 64 * 128 * 2;      // 32 KB
    _Float16* h1h = (_Float16*)w;  w += (size_t)2 * NN * 256 * 2;      // 4 MB
    char* shared8 = w;             w += (size_t)8 * 1024 * 1024;       // 8 MB
    float* bnp = (float*)w;        w += (size_t)2 * 32 * 128 * 4;      // 32 KB
    float* stats = (float*)w;      w += 256 * 4;
    float* hpart = (float*)w;      w += 1024 * 4;

    _Float16* h2h  = (_Float16*)shared8;                 // 2 MB
    float* h3  = (float*)(shared8 + 2 * 1024 * 1024);    // 2 MB
    float* hn  = (float*)(shared8 + 4 * 1024 * 1024);    // 2 MB
    float* att = (float*)(shared8 + 6 * 1024 * 1024);    // 2 MB

    const dim3 blk(256);

    // ---- weight conversion (single fused kernel) -------------------------
    CvtP cp;
    cp.j[0] = { e1_W1, W1h,             262144 };
    cp.j[1] = { e2_W1, W1h + 256 * NN,  262144 };
    cp.j[2] = { e1_W2, W2h,             8192 };
    cp.j[3] = { e2_W2, W2h + 128 * 256, 8192 };
    cp.j[4] = { e1_W3, W3h,             2048 };
    cp.j[5] = { e2_W3, W3h + 64 * 128,  2048 };
    cvt_all_kernel<<<dim3(2128), blk, 0, stream>>>(cp);

    // ---- fc1: [4096,4096] -> 256, in-block split-K x4, fused bias+ReLU ---
    GemmP p1 = { {x1, x2}, {W1h, W1h + 256 * NN}, {e1_b1, e2_b1},
                 {h1h, h1h + (size_t)NN * 256} };
    fc1_kernel<<<dim3(NN / 32, 2), dim3(1024), 0, stream>>>(p1);

    // ---- fc2: [4096,256] -> 128, ReLU, fp16 out --------------------------
    GemmP p2 = { {h1h, h1h + (size_t)NN * 256}, {W2h, W2h + 128 * 256}, {e1_b2, e2_b2},
                 {h2h, h2h + (size_t)NN * 128} };
    gemm_kernel<2, true, 0, true><<<dim3(1, NN / 32, 2), blk, 0, stream>>>(p2, NN, 256, 256);

    // ---- fc3: [4096,128] -> 64, fp32 out (BN follows) --------------------
    GemmP p3 = { {h2h, h2h + (size_t)NN * 128}, {W3h, W3h + 64 * 128}, {e1_b3, e2_b3},
                 {h3, h3 + ENC_OUT} };
    gemm_kernel<1, true, 1, false><<<dim3(1, NN / 32, 2), blk, 0, stream>>>(p3, NN, 128, 128);

    // ---- BatchNorm (train-mode) + ReLU -----------------------------------
    bn_stat1_kernel<<<dim3(32, 2), blk, 0, stream>>>(h3, bnp);
    bn_stat2_kernel<<<dim3(2), dim3(64), 0, stream>>>(bnp, stats);
    bn_apply_kernel<<<dim3(2 * ENC_OUT / 256), blk, 0, stream>>>(h3, stats, e1_g, e2_g,
                                                                 e1_be, e2_be, hn);

    // ---- self-attention --------------------------------------------------
    att_kernel<<<dim3(NN, 2), blk, 0, stream>>>(adj1, adj2, alpha1, alpha2, hn, att);

    // ---- head ------------------------------------------------------------
    final_partial_kernel<<<dim3(512), blk, 0, stream>>>(att, Wc, hpart);
    final_reduce_kernel<<<dim3(1), blk, 0, stream>>>(hpart, bc, (float*)d_out);
}

// Round 3
// 435.026 us; speedup vs baseline: 1.1737x; 1.0798x over previous
//
#include <hip/hip_runtime.h>
#include <cstddef>
#include <cstdint>

// ---------------------------------------------------------------------------
// GraphClassifier round 6.
// fc1 v3: BK=64 x 16 steps, A global->register (full-line, dbuf, 1-step
// prefetch) + in-register cvt + tiny f16 frag-tile exchange in LDS (32 KB,
// XOR-swizzled, read-side conflict-free), B single-buffered in registers
// issued a phase early, ONE raw s_barrier per 64-K step (16 total).
// No manual vmcnt ledger: all global loads are register loads, compiler
// emits precise counted waits.
// att_kernel: ballot-based neighbor compaction (atomics eliminated).
// fc2/fc3: counted vmcnt(2) instead of vmcnt(0) (A-prefetch stays in
// flight across MFMA phase), issue order pinned with sched_barrier.
// ---------------------------------------------------------------------------

#define NN 4096
#define HDIM 64
#define ENC_OUT (NN * HDIM)   // 262144 = 2^18

typedef _Float16 half8 __attribute__((ext_vector_type(8)));
typedef _Float16 half4 __attribute__((ext_vector_type(4)));
typedef float v4f __attribute__((ext_vector_type(4)));

__device__ __forceinline__ void gld_lds16(const void* g, void* l) {
    __builtin_amdgcn_global_load_lds(
        (const __attribute__((address_space(1))) void*)g,
        (__attribute__((address_space(3))) void*)l, 16, 0, 0);
}

struct GemmP {
    const void*     A[2];     // fp32 (fc1) or fp16, row-major [M,lda]
    const _Float16* B[2];     // weight fp16, row-major [N,lda]
    const float*    bias[2];
    void*           C[2];     // OUT=0: fp16 per-enc; OUT=1: fp32 per-enc
};

// ---------------------------------------------------------------------------
// fc1: C[m,n] = relu(bias[n] + sum_k A[m,k]*B[n,k]),  M=4096 N=256 K=4096.
// Block: 1024 thr = 16 waves, wave w -> (kg=w>>2, ng=w&3), BM=32, BK=64.
// Per step: wave loads its 8 A-rows (2 full-line float4 instrs, dbuf,
// prefetched 1 step ahead), cvts in-register, publishes 2 half4 into the
// kg-shared f16 frag tile [kq2][row32][64B] (XOR-swizzled: chunk' =
// chunk ^ ((row>>1)&3) -> frag ds_read_b128 is 2-way = free). B: 8 half8
// register loads issued at step start (latency covered by cvt+barrier).
// One s_barrier per step; f16 tile double-buffered (write s+2 separated
// from read s by barrier s+1). kg-reduction in LDS + bias/ReLU epilogue.
// ---------------------------------------------------------------------------
__global__ __launch_bounds__(1024) void fc1_kernel(GemmP p)
{
    __shared__ char lds[64 * 1024];
    // in-loop: f16 tiles [kg][buf2][4KB] in first 32 KB
    // epilogue reduction reuses all 64 KB.

    const int tid = threadIdx.x;
    const int wave = tid >> 6, lane = tid & 63;
    const int l16 = lane & 15, quad = lane >> 4;
    const int kg = wave >> 2, ng = wave & 3;
    const int enc = blockIdx.y;
    const int m0 = blockIdx.x * 32;
    const int kOff = kg * 1024;
    constexpr int NS = 16;            // 16 steps of BK=64

    const float* __restrict__ A = (const float*)p.A[enc];
    const _Float16* __restrict__ Bp = p.B[enc];

    // ---- A staging geometry: wave covers rows ng*8..+8, 64 k per step ----
    // instr j (j=0,1): lane (srow = ng*8 + lane>>3, sc = lane&7) reads
    // floats [j*32 + sc*4, +4) -> 8 rows x 128B contiguous per instr.
    const int srow = ng * 8 + (lane >> 3);
    const int sc   = lane & 7;
    const float* asrc = A + (size_t)(m0 + srow) * NN + kOff + sc * 4;

    // f16 tile write: halfs [c*4..+4) of (srow) go to kq=j, byte =
    // j*2048 + srow*64 + chunk'*16 + (sc&1)*8, chunk' = (sc>>1)^((srow>>1)&3)
    char* f16kg = &lds[kg * 8192];
    const int wof = srow * 64 + (((sc >> 1) ^ ((srow >> 1) & 3)) * 16) + (sc & 1) * 8;

    // frag read: row = mi*16 + l16, chunk' = quad ^ ((row>>1)&3)
    const int r0 = l16, r1 = 16 + l16;
    const int rd0 = r0 * 64 + ((quad ^ ((r0 >> 1) & 3)) * 16);
    const int rd1 = r1 * 64 + ((quad ^ ((r1 >> 1) & 3)) * 16);

    // B: frag-ordered register loads (16 rows x 64B full lines per instr)
    const _Float16* bsrc = Bp + (size_t)(ng * 64 + l16) * NN + kOff + quad * 8;

    v4f acc[2][4];
#pragma unroll
    for (int mi = 0; mi < 2; mi++)
#pragma unroll
        for (int ni = 0; ni < 4; ni++) acc[mi][ni] = (v4f){0.f, 0.f, 0.f, 0.f};

    float4 aA[2], aB[2];
    // prologue: A(0) -> aA
    aA[0] = *(const float4*)(asrc);
    aA[1] = *(const float4*)(asrc + 32);

    auto body = [&](int s, float4* cur, float4* nxt, bool last) {
        // 1. B(s) -> regs (issued first; latency hidden under cvt+barrier)
        half8 b[2][4];
#pragma unroll
        for (int kq = 0; kq < 2; kq++)
#pragma unroll
            for (int ni = 0; ni < 4; ni++)
                b[kq][ni] = *(const half8*)(bsrc + (size_t)ni * 16 * NN + s * 64 + kq * 32);
        // 2. A(s+1) prefetch -> regs
        if (!last) {
            nxt[0] = *(const float4*)(asrc + (s + 1) * 64);
            nxt[1] = *(const float4*)(asrc + (s + 1) * 64 + 32);
        }
        __builtin_amdgcn_sched_barrier(0);   // pin early issue of all loads

        // 3. cvt A(s) regs -> f16 tile (compiler inserts exact vmcnt wait)
        char* fb = f16kg + (s & 1) * 4096;
#pragma unroll
        for (int j = 0; j < 2; j++) {
            half4 h;
            h[0] = (_Float16)cur[j].x; h[1] = (_Float16)cur[j].y;
            h[2] = (_Float16)cur[j].z; h[3] = (_Float16)cur[j].w;
            *(half4*)(fb + j * 2048 + wof) = h;
        }
        // 4. publish
        __builtin_amdgcn_s_waitcnt(0xC07F);  // lgkmcnt(0)
        __builtin_amdgcn_sched_barrier(0);
        __builtin_amdgcn_s_barrier();
        __builtin_amdgcn_sched_barrier(0);
        // 5. consume: frag reads + MFMA (compiler waits lgkm/vm precisely)
        half8 a0k0 = *(const half8*)(fb + rd0);
        half8 a1k0 = *(const half8*)(fb + rd1);
        half8 a0k1 = *(const half8*)(fb + 2048 + rd0);
        half8 a1k1 = *(const half8*)(fb + 2048 + rd1);
#pragma unroll
        for (int ni = 0; ni < 4; ni++) {
            acc[0][ni] = __builtin_amdgcn_mfma_f32_16x16x32_f16(a0k0, b[0][ni], acc[0][ni], 0, 0, 0);
            acc[0][ni] = __builtin_amdgcn_mfma_f32_16x16x32_f16(a0k1, b[1][ni], acc[0][ni], 0, 0, 0);
            acc[1][ni] = __builtin_amdgcn_mfma_f32_16x16x32_f16(a1k0, b[0][ni], acc[1][ni], 0, 0, 0);
            acc[1][ni] = __builtin_amdgcn_mfma_f32_16x16x32_f16(a1k1, b[1][ni], acc[1][ni], 0, 0, 0);
        }
    };

    for (int s = 0; s < NS - 2; s += 2) {
        body(s, aA, aB, false);
        body(s + 1, aB, aA, false);
    }
    body(NS - 2, aA, aB, false);
    body(NS - 1, aB, aA, true);

    // ---- in-block kg-reduction (fp32, via LDS) ---------------------------
    __syncthreads();

    if (kg >= 2) {
        const int sidx = (kg - 2) * 4 + ng;
#pragma unroll
        for (int mi = 0; mi < 2; mi++)
#pragma unroll
            for (int ni = 0; ni < 4; ni++)
                *(v4f*)&lds[sidx * 8192 + (mi * 4 + ni) * 1024 + lane * 16] = acc[mi][ni];
    }
    __syncthreads();
    if (kg < 2) {
        const int sidx = kg * 4 + ng;
#pragma unroll
        for (int mi = 0; mi < 2; mi++)
#pragma unroll
            for (int ni = 0; ni < 4; ni++)
                acc[mi][ni] += *(const v4f*)&lds[sidx * 8192 + (mi * 4 + ni) * 1024 + lane * 16];
    }
    __syncthreads();

    if (kg == 1) {
#pragma unroll
        for (int mi = 0; mi < 2; mi++)
#pragma unroll
            for (int ni = 0; ni < 4; ni++)
                *(v4f*)&lds[ng * 8192 + (mi * 4 + ni) * 1024 + lane * 16] = acc[mi][ni];
    }
    __syncthreads();

    if (kg == 0) {
        _Float16* __restrict__ h1 = (_Float16*)p.C[enc];
        const float* __restrict__ bs = p.bias[enc];
#pragma unroll
        for (int mi = 0; mi < 2; mi++)
#pragma unroll
            for (int ni = 0; ni < 4; ni++) {
                v4f v = acc[mi][ni] + *(const v4f*)&lds[ng * 8192 + (mi * 4 + ni) * 1024 + lane * 16];
                const int col = ng * 64 + ni * 16 + l16;
                const float b = bs[col];
#pragma unroll
                for (int i = 0; i < 4; i++) {
                    const int row = m0 + mi * 16 + quad * 4 + i;
                    h1[(size_t)row * 256 + col] = (_Float16)fmaxf(v[i] + b, 0.f);
                }
            }
    }
}

// ---------------------------------------------------------------------------
// MFMA GEMM (fc2/fc3): C[m,n] = act(bias[n] + sum_k A[m,k]*B[n,k])
// BM=32, BN=NI*64 (full N per block). 256 thr = 4 waves.
// Counted vmcnt(2): A(s+1) prefetch stays in flight across MFMA phase.
// Issue order pinned: [glds B(s)] < [loadA(s+1)] < wait.
// ---------------------------------------------------------------------------
template<int NI, bool A16, int OUT, bool RELU>
__global__ __launch_bounds__(256) void gemm_kernel(GemmP p, int M, int lda, int Ksub)
{
    constexpr int N = NI * 64;
    __shared__ char Bs[NI * 4 * 1024];   // NI*4 frag-tiles of 1 KB

    const int tid = threadIdx.x;
    const int wave = tid >> 6, lane = tid & 63;
    const int l16 = lane & 15, quad = lane >> 4;
    const int enc = blockIdx.z, split = blockIdx.x;
    const int m0 = blockIdx.y * 32;
    const int kOff = split * Ksub;
    const int nsteps = Ksub >> 5;

    const _Float16* __restrict__ Bp = p.B[enc];
    const char* Abase = (const char*)p.A[enc];

    const size_t aoff0 = (size_t)(m0 + l16) * lda + kOff + quad * 8;
    const size_t aoff1 = aoff0 + (size_t)16 * lda;

    half8 na0, na1;
    float4 nf0lo, nf0hi, nf1lo, nf1hi;
    auto loadA = [&](int s) {
        if constexpr (A16) {
            const _Float16* A = (const _Float16*)Abase;
            na0 = *(const half8*)(A + aoff0 + s * 32);
            na1 = *(const half8*)(A + aoff1 + s * 32);
        } else {
            const float* A = (const float*)Abase;
            nf0lo = *(const float4*)(A + aoff0 + s * 32);
            nf0hi = *(const float4*)(A + aoff0 + s * 32 + 4);
            nf1lo = *(const float4*)(A + aoff1 + s * 32);
            nf1hi = *(const float4*)(A + aoff1 + s * 32 + 4);
        }
    };

    v4f acc[2][NI];
#pragma unroll
    for (int mi = 0; mi < 2; mi++)
#pragma unroll
        for (int ni = 0; ni < NI; ni++) acc[mi][ni] = (v4f){0.f, 0.f, 0.f, 0.f};

    loadA(0);

    for (int s = 0; s < nsteps; ++s) {
        // stage B(s) into this wave's private frag-tiles (oldest vmem ops)
#pragma unroll
        for (int ni = 0; ni < NI; ni++) {
            const int T = wave * NI + ni;
            const _Float16* g = Bp + (size_t)(T * 16 + l16) * lda + kOff + s * 32 + quad * 8;
            gld_lds16(g, &Bs[T * 1024]);
        }
        __builtin_amdgcn_sched_barrier(0);
        // consume prefetched A(s), then prefetch A(s+1)
        half8 ca0, ca1;
        if constexpr (A16) {
            ca0 = na0; ca1 = na1;
        } else {
            ca0[0] = (_Float16)nf0lo.x; ca0[1] = (_Float16)nf0lo.y;
            ca0[2] = (_Float16)nf0lo.z; ca0[3] = (_Float16)nf0lo.w;
            ca0[4] = (_Float16)nf0hi.x; ca0[5] = (_Float16)nf0hi.y;
            ca0[6] = (_Float16)nf0hi.z; ca0[7] = (_Float16)nf0hi.w;
            ca1[0] = (_Float16)nf1lo.x; ca1[1] = (_Float16)nf1lo.y;
            ca1[2] = (_Float16)nf1lo.z; ca1[3] = (_Float16)nf1lo.w;
            ca1[4] = (_Float16)nf1hi.x; ca1[5] = (_Float16)nf1hi.y;
            ca1[6] = (_Float16)nf1hi.z; ca1[7] = (_Float16)nf1hi.w;
        }
        const bool more = (s + 1 < nsteps);
        if (more) loadA(s + 1);
        __builtin_amdgcn_sched_barrier(0);

        // counted drain: glds B(s) resident; A(s+1) (2 loads) stays in flight
        if (more) __builtin_amdgcn_s_waitcnt(0x0F72);   // vmcnt(2)
        else      __builtin_amdgcn_s_waitcnt(0x0F70);   // vmcnt(0)
        __builtin_amdgcn_sched_barrier(0);

#pragma unroll
        for (int ni = 0; ni < NI; ni++) {
            half8 bf = *(const half8*)&Bs[(wave * NI + ni) * 1024 + lane * 16];
            acc[0][ni] = __builtin_amdgcn_mfma_f32_16x16x32_f16(ca0, bf, acc[0][ni], 0, 0, 0);
            acc[1][ni] = __builtin_amdgcn_mfma_f32_16x16x32_f16(ca1, bf, acc[1][ni], 0, 0, 0);
        }
    }

    // epilogue
#pragma unroll
    for (int mi = 0; mi < 2; mi++)
#pragma unroll
        for (int ni = 0; ni < NI; ni++) {
            const int col = wave * NI * 16 + ni * 16 + l16;
#pragma unroll
            for (int i = 0; i < 4; i++) {
                const int row = m0 + mi * 16 + quad * 4 + i;
                float v = acc[mi][ni][i];
                v += p.bias[enc][col];
                if (RELU) v = fmaxf(v, 0.f);
                if constexpr (OUT == 0)
                    ((_Float16*)p.C[enc])[(size_t)row * N + col] = (_Float16)v;
                else
                    ((float*)p.C[enc])[(size_t)row * N + col] = v;
            }
        }
}

// ---------------------------------------------------------------------------
// fused fp32 -> fp16 conversion for all six weight matrices
// ---------------------------------------------------------------------------
struct CvtJob { const float* s; _Float16* d; int n4; };
struct CvtP { CvtJob j[6]; };

__global__ __launch_bounds__(256) void cvt_all_kernel(CvtP p)
{
    int i = blockIdx.x * 256 + threadIdx.x;
#pragma unroll
    for (int k = 0; k < 6; k++) {
        if (i < p.j[k].n4) {
            float4 v = ((const float4*)p.j[k].s)[i];
            half4 h;
            h[0] = (_Float16)v.x; h[1] = (_Float16)v.y;
            h[2] = (_Float16)v.z; h[3] = (_Float16)v.w;
            ((half4*)p.j[k].d)[i] = h;
            return;
        }
        i -= p.j[k].n4;
    }
}

// ---------------------------------------------------------------------------
// BatchNorm stats (two-phase, coalesced) + apply
// ---------------------------------------------------------------------------
__global__ __launch_bounds__(256) void bn_stat1_kernel(const float* __restrict__ h3,
                                                       float* __restrict__ bnp)
{
    const int enc = blockIdx.y, b = blockIdx.x;
    const int c = threadIdx.x & 63, rg = threadIdx.x >> 6;
    const float* h = h3 + (size_t)enc * ENC_OUT + (size_t)b * 128 * HDIM;
    float s = 0.f, q = 0.f;
    for (int r = rg; r < 128; r += 4) {
        float v = h[(size_t)r * HDIM + c];
        s += v; q += v * v;
    }
    __shared__ float ss[4][64], sq[4][64];
    ss[rg][c] = s; sq[rg][c] = q;
    __syncthreads();
    if (threadIdx.x < 64) {
        float S = ss[0][c] + ss[1][c] + ss[2][c] + ss[3][c];
        float Q = sq[0][c] + sq[1][c] + sq[2][c] + sq[3][c];
        bnp[(size_t)(enc * 32 + b) * 128 + c] = S;
        bnp[(size_t)(enc * 32 + b) * 128 + 64 + c] = Q;
    }
}

__global__ void bn_stat2_kernel(const float* __restrict__ bnp, float* __restrict__ stats)
{
    const int enc = blockIdx.x, c = threadIdx.x;  // 64 threads
    float s = 0.f, q = 0.f;
    for (int b = 0; b < 32; b++) {
        s += bnp[(size_t)(enc * 32 + b) * 128 + c];
        q += bnp[(size_t)(enc * 32 + b) * 128 + 64 + c];
    }
    float mean = s * (1.f / NN);
    float var = q * (1.f / NN) - mean * mean;
    stats[enc * 128 + c] = mean;
    stats[enc * 128 + 64 + c] = rsqrtf(var + 1e-5f);
}

__global__ __launch_bounds__(256) void bn_apply_kernel(const float* __restrict__ h3,
                                                       const float* __restrict__ stats,
                                                       const float* __restrict__ g0,
                                                       const float* __restrict__ g1,
                                                       const float* __restrict__ be0,
                                                       const float* __restrict__ be1,
                                                       float* __restrict__ hn)
{
    const int idx = blockIdx.x * 256 + threadIdx.x;
    const int enc = idx >> 18;
    const int c = idx & 63;
    const float* g = enc ? g1 : g0;
    const float* be = enc ? be1 : be0;
    const float m = stats[enc * 128 + c];
    const float rs = stats[enc * 128 + 64 + c];
    float v = (h3[idx] - m) * rs * g[c] + be[c];
    hn[idx] = fmaxf(v, 0.f);
}

// ---------------------------------------------------------------------------
// Self-attention: masked mean over ~41 neighbors + residual.
// Ballot-based compaction (no atomics): wave w scans cols [w*1024,+1024)
// in 16 ballot rounds; cross-wave prefix via 4-entry LDS; pass-2 scatter.
// ---------------------------------------------------------------------------
__global__ __launch_bounds__(256) void att_kernel(const float* __restrict__ adj1,
                                                  const float* __restrict__ adj2,
                                                  const float* __restrict__ al1,
                                                  const float* __restrict__ al2,
                                                  const float* __restrict__ hn,
                                                  float* __restrict__ out)
{
    const int enc = blockIdx.y;
    const float* adj = enc ? adj2 : adj1;
    const float* al = enc ? al2 : al1;
    const float* h = hn + (size_t)enc * ENC_OUT;
    float* o = out + (size_t)enc * ENC_OUT;
    const int i = blockIdx.x;
    const int tid = threadIdx.x;
    const int lane = tid & 63;
    const int w = tid >> 6;

    __shared__ int s_j[192];
    __shared__ float s_w[192];
    __shared__ int s_wc[4];
    __shared__ float s_acc[4][64];

    const float* arow = adj + (size_t)i * NN;

    // pass 1: ballot + count
    unsigned long long masks[16];
    int cnt_w = 0;
#pragma unroll
    for (int r = 0; r < 16; ++r) {
        float a = arow[w * 1024 + r * 64 + lane];
        unsigned long long m = __ballot(a == 1.f);
        masks[r] = m;
        cnt_w += __popcll(m);
    }
    if (lane == 0) s_wc[w] = cnt_w;
    __syncthreads();

    const int c0 = s_wc[0], c1 = s_wc[1], c2 = s_wc[2], c3 = s_wc[3];
    const int cnt = c0 + c1 + c2 + c3;                 // true degree
    const int cc = min(cnt, 192);
    int run = (w > 0 ? c0 : 0) + (w > 1 ? c1 : 0) + (w > 2 ? c2 : 0);

    // pass 2: scatter indices
#pragma unroll
    for (int r = 0; r < 16; ++r) {
        unsigned long long m = masks[r];
        if ((m >> lane) & 1ull) {
            int pos = run + __popcll(m & ((1ull << lane) - 1ull));
            if (pos < 192) s_j[pos] = w * 1024 + r * 64 + lane;
        }
        run += __popcll(m);
    }
    __syncthreads();

    // gather alpha weights
    const float* alrow = al + (size_t)i * NN;
    for (int t = tid; t < cc; t += 256) s_w[t] = alrow[s_j[t]];
    __syncthreads();

    // accumulate
    const int c = tid & 63;
    const int g = tid >> 6;
    float acc = 0.f;
    for (int t = g; t < cc; t += 4) acc += s_w[t] * h[(size_t)s_j[t] * HDIM + c];
    s_acc[g][c] = acc;
    __syncthreads();

    if (tid < 64) {
        float r;
        if (cnt != 0) {
            r = (s_acc[0][c] + s_acc[1][c] + s_acc[2][c] + s_acc[3][c]) / (float)cnt
                + h[(size_t)i * HDIM + c];
        } else {
            r = 0.f;
        }
        o[(size_t)i * HDIM + c] = r;
    }
}

// ---------------------------------------------------------------------------
// Head: 512-block two-phase reduction
// ---------------------------------------------------------------------------
#define FDIM (2 * ENC_OUT)

__global__ __launch_bounds__(256) void final_partial_kernel(const float* __restrict__ feat,
                                                            const float* __restrict__ Wc,
                                                            float* __restrict__ partial)
{
    const int gt = blockIdx.x * 256 + threadIdx.x;   // 131072 threads
    float p0 = 0.f, p1 = 0.f;
    for (int f = gt; f < FDIM; f += 131072) {
        float x = feat[f];
        p0 += x * Wc[f];
        p1 += x * Wc[FDIM + f];
    }
    __shared__ float r0[256], r1[256];
    r0[threadIdx.x] = p0;
    r1[threadIdx.x] = p1;
    __syncthreads();
    for (int off = 128; off > 0; off >>= 1) {
        if (threadIdx.x < off) {
            r0[threadIdx.x] += r0[threadIdx.x + off];
            r1[threadIdx.x] += r1[threadIdx.x + off];
        }
        __syncthreads();
    }
    if (threadIdx.x == 0) {
        partial[blockIdx.x * 2 + 0] = r0[0];
        partial[blockIdx.x * 2 + 1] = r1[0];
    }
}

__global__ __launch_bounds__(256) void final_reduce_kernel(const float* __restrict__ partial,
                                                           const float* __restrict__ bc,
                                                           float* __restrict__ out)
{
    // partial: 512 x 2 floats interleaved; 256 threads, 2 float2 each
    const int t = threadIdx.x;
    float2 v = ((const float2*)partial)[t];
    float2 w = ((const float2*)partial)[t + 256];
    __shared__ float r0[256], r1[256];
    r0[t] = v.x + w.x;
    r1[t] = v.y + w.y;
    __syncthreads();
    for (int off = 128; off > 0; off >>= 1) {
        if (t < off) {
            r0[t] += r0[t + off];
            r1[t] += r1[t + off];
        }
        __syncthreads();
    }
    if (t == 0) {
        out[0] = bc[0] + r0[0];
        out[1] = bc[1] + r1[0];
    }
}

// ---------------------------------------------------------------------------

extern "C" void kernel_launch(void* const* d_in, const int* in_sizes, int n_in,
                              void* d_out, int out_size, void* d_ws, size_t ws_size,
                              hipStream_t stream)
{
    const float* x1    = (const float*)d_in[0];
    const float* x2    = (const float*)d_in[1];
    const float* adj1  = (const float*)d_in[2];
    const float* adj2  = (const float*)d_in[3];
    const float* e1_W1 = (const float*)d_in[4];
    const float* e1_b1 = (const float*)d_in[5];
    const float* e1_W2 = (const float*)d_in[6];
    const float* e1_b2 = (const float*)d_in[7];
    const float* e1_W3 = (const float*)d_in[8];
    const float* e1_b3 = (const float*)d_in[9];
    const float* e1_g  = (const float*)d_in[10];
    const float* e1_be = (const float*)d_in[11];
    const float* e2_W1 = (const float*)d_in[12];
    const float* e2_b1 = (const float*)d_in[13];
    const float* e2_W2 = (const float*)d_in[14];
    const float* e2_b2 = (const float*)d_in[15];
    const float* e2_W3 = (const float*)d_in[16];
    const float* e2_b3 = (const float*)d_in[17];
    const float* e2_g  = (const float*)d_in[18];
    const float* e2_be = (const float*)d_in[19];
    const float* alpha1 = (const float*)d_in[20];
    const float* alpha2 = (const float*)d_in[21];
    const float* Wc    = (const float*)d_in[22];
    const float* bc    = (const float*)d_in[23];
    (void)in_sizes; (void)n_in; (void)out_size; (void)ws_size;

    // ---- workspace layout (~17.0 MB) -------------------------------------
    char* w = (char*)d_ws;
    _Float16* W1h = (_Float16*)w;  w += (size_t)2 * 256 * NN * 2;      // 4 MB
    _Float16* W2h = (_Float16*)w;  w += (size_t)2 * 128 * 256 * 2;     // 128 KB
    _Float16* W3h = (_Float16*)w;  w += (size_t)2 * 64 * 128 * 2;      // 32 KB
    _Float16* h1h = (_Float16*)w;  w += (size_t)2 * NN * 256 * 2;      // 4 MB
    char* shared8 = w;             w += (size_t)8 * 1024 * 1024;       // 8 MB
    float* bnp = (float*)w;        w += (size_t)2 * 32 * 128 * 4;      // 32 KB
    float* stats = (float*)w;      w += 256 * 4;
    float* hpart = (float*)w;      w += 1024 * 4;

    _Float16* h2h  = (_Float16*)shared8;                 // 2 MB
    float* h3  = (float*)(shared8 + 2 * 1024 * 1024);    // 2 MB
    float* hn  = (float*)(shared8 + 4 * 1024 * 1024);    // 2 MB
    float* att = (float*)(shared8 + 6 * 1024 * 1024);    // 2 MB

    const dim3 blk(256);

    // ---- weight conversion (single fused kernel) -------------------------
    CvtP cp;
    cp.j[0] = { e1_W1, W1h,             262144 };
    cp.j[1] = { e2_W1, W1h + 256 * NN,  262144 };
    cp.j[2] = { e1_W2, W2h,             8192 };
    cp.j[3] = { e2_W2, W2h + 128 * 256, 8192 };
    cp.j[4] = { e1_W3, W3h,             2048 };
    cp.j[5] = { e2_W3, W3h + 64 * 128,  2048 };
    cvt_all_kernel<<<dim3(2128), blk, 0, stream>>>(cp);

    // ---- fc1: [4096,4096] -> 256, in-block split-K x4, fused bias+ReLU ---
    GemmP p1 = { {x1, x2}, {W1h, W1h + 256 * NN}, {e1_b1, e2_b1},
                 {h1h, h1h + (size_t)NN * 256} };
    fc1_kernel<<<dim3(NN / 32, 2), dim3(1024), 0, stream>>>(p1);

    // ---- fc2: [4096,256] -> 128, ReLU, fp16 out --------------------------
    GemmP p2 = { {h1h, h1h + (size_t)NN * 256}, {W2h, W2h + 128 * 256}, {e1_b2, e2_b2},
                 {h2h, h2h + (size_t)NN * 128} };
    gemm_kernel<2, true, 0, true><<<dim3(1, NN / 32, 2), blk, 0, stream>>>(p2, NN, 256, 256);

    // ---- fc3: [4096,128] -> 64, fp32 out (BN follows) --------------------
    GemmP p3 = { {h2h, h2h + (size_t)NN * 128}, {W3h, W3h + 64 * 128}, {e1_b3, e2_b3},
                 {h3, h3 + ENC_OUT} };
    gemm_kernel<1, true, 1, false><<<dim3(1, NN / 32, 2), blk, 0, stream>>>(p3, NN, 128, 128);

    // ---- BatchNorm (train-mode) + ReLU -----------------------------------
    bn_stat1_kernel<<<dim3(32, 2), blk, 0, stream>>>(h3, bnp);
    bn_stat2_kernel<<<dim3(2), dim3(64), 0, stream>>>(bnp, stats);
    bn_apply_kernel<<<dim3(2 * ENC_OUT / 256), blk, 0, stream>>>(h3, stats, e1_g, e2_g,
                                                                 e1_be, e2_be, hn);

    // ---- self-attention --------------------------------------------------
    att_kernel<<<dim3(NN, 2), blk, 0, stream>>>(adj1, adj2, alpha1, alpha2, hn, att);

    // ---- head ------------------------------------------------------------
    final_partial_kernel<<<dim3(512), blk, 0, stream>>>(att, Wc, hpart);
    final_reduce_kernel<<<dim3(1), blk, 0, stream>>>(hpart, bc, (float*)d_out);
}